// Round 15
// baseline (42.899 us; speedup 1.0000x reference)
//
#include <hip/hip_runtime.h>
#include <math.h>

#define DM 512
#define LSEQ 8192
#define NV 8
#define TOK 1608
#define NTHR 256     // 4 waves; wave = 8 rows x 256 cols; thread = 8r x 4c

typedef _Float16 h2 __attribute__((ext_vector_type(2)));
typedef float f4n __attribute__((ext_vector_type(4)));   // native float4 for builtins

// Heavy-first segment order. seg -> v: {6,7,4,5,2,3,0,1}
__device__ __constant__ int c_segv[8]   = {6, 7, 4, 5, 2, 3, 0, 1};
// blocks/seg = 2 halves * 32 batches * chunks_per_batch, where rows/block =
// {v0,v1:128, v2..v5:64, v6,v7:32}: chunks/batch = {4,4,2,2,2,2,1,1}
// counts: v6:64, v7:64, v4:128, v5:128, v2:128, v3:128, v0:256, v1:256
__device__ __constant__ int c_cum[9]    = {0, 64, 128, 256, 384, 512, 640, 896, 1152};
__device__ __constant__ int c_lgch[8]   = {0, 0, 1, 1, 1, 1, 2, 2};   // log2(chunks/batch) by seg
// indexed by v:
__device__ __constant__ int c_tokoff[8] = {0, 513, 1026, 1155, 1284, 1413, 1542, 1575};
__device__ __constant__ int c_np[8]     = {512, 512, 128, 128, 128, 128, 32, 32};
__device__ __constant__ int c_pl[8]     = {16, 16, 32, 32, 64, 64, 128, 128};
__device__ __constant__ int c_sf[8]     = {1, 1, 2, 2, 1, 1, 2, 2};
__device__ __constant__ int c_rpb[8]    = {128, 128, 64, 64, 64, 64, 32, 32};  // rows per block
// packed-half2-weight word offsets within d_ws per v:
// w16@0 (8 k2-rows), w32@4096 (16), w64@12288 (32), w128@28672 (64)
__device__ __constant__ int c_wtoff[8]  = {0, 0, 4096, 4096, 12288, 12288, 28672, 28672};

__device__ __forceinline__ float fdot2f(h2 a, h2 b, float c) {
#if __has_builtin(__builtin_amdgcn_fdot2)
    return __builtin_amdgcn_fdot2(a, b, c, false);
#else
    return fmaf((float)a.y, (float)b.y, fmaf((float)a.x, (float)b.x, c));
#endif
}
__device__ __forceinline__ h2 bch2(unsigned u) { return __builtin_bit_cast(h2, u); }

__device__ __forceinline__ void nt_store4(float* p, float4 v) {
#if __has_builtin(__builtin_nontemporal_store)
    f4n t; t.x = v.x; t.y = v.y; t.z = v.z; t.w = v.w;
    __builtin_nontemporal_store(t, reinterpret_cast<f4n*>(p));
#else
    *reinterpret_cast<float4*>(p) = v;
#endif
}

// ---------------------------------------------------------------------------
// Setup: 120 blocks pack transposed fp16 weights wt_h[k2][512] (half2 words).
// ---------------------------------------------------------------------------
__global__ __launch_bounds__(512) void setup_kernel(
    const float* __restrict__ w16, const float* __restrict__ w32,
    const float* __restrict__ w64, const float* __restrict__ w128,
    float* __restrict__ ws)
{
    int j = blockIdx.x;                // 120 half2-rows across the 4 matrices
    int d = threadIdx.x;
    const float* w; int pl, k2, off;
    if (j < 8)       { w = w16;  pl = 16;  k2 = j;      off = 0; }
    else if (j < 24) { w = w32;  pl = 32;  k2 = j - 8;  off = 4096; }
    else if (j < 56) { w = w64;  pl = 64;  k2 = j - 24; off = 12288; }
    else             { w = w128; pl = 128; k2 = j - 56; off = 28672; }
    float2 p = *reinterpret_cast<const float2*>(w + (size_t)d * pl + 2 * k2);
    h2 h; h.x = (_Float16)p.x; h.y = (_Float16)p.y;
    reinterpret_cast<unsigned*>(ws)[off + k2 * DM + d] = __builtin_bit_cast(unsigned, h);
}

// 4-col dot update for row r with patch half2 P and W quad X (cols c0..c0+3)
#define DOT4(r, P, X)                                           \
    acc[r][0] = fdot2f(P, bch2((X).x), acc[r][0]);              \
    acc[r][1] = fdot2f(P, bch2((X).y), acc[r][1]);              \
    acc[r][2] = fdot2f(P, bch2((X).z), acc[r][2]);              \
    acc[r][3] = fdot2f(P, bch2((X).w), acc[r][3]);

// ---------------------------------------------------------------------------
// Main kernel. Blocks [0,1152): one block = rpb rows x 256 cols (col-half h),
// rpb = 128/64/32 by pl. Stage ALL rows once (one sync), then loop RG = rpb/32
// row-groups, each running R7's exact 4-k ping-pong K-loop + epilogue.
// Groups >= 1 hit L1 for W (no cold-miss chain), amortizing per-block costs.
// Blocks [1152,1160): global-token rows.
// ---------------------------------------------------------------------------
__global__ __launch_bounds__(NTHR, 6) void patch_embed_kernel(
    const float* __restrict__ x,
    const float* __restrict__ b16,  const float* __restrict__ b32,
    const float* __restrict__ b64,  const float* __restrict__ b128,
    const float* __restrict__ glb,  const float* __restrict__ chan,
    const float* __restrict__ ws,   float* __restrict__ out)
{
    extern __shared__ float ldsf[];              // rpb * pl/2 half2 words, <= 8 KB
    unsigned* ldsu = reinterpret_cast<unsigned*>(ldsf);
    int bid = blockIdx.x;
    const int tid = threadIdx.x;

    if (bid >= 1152) {                           // global-token rows (8 blocks)
        int v = bid - 1152;
        int d2 = tid << 1;
        float2 g = *reinterpret_cast<const float2*>(glb + d2);
        float2 c = *reinterpret_cast<const float2*>(chan + v * DM + d2);
        float2 o; o.x = g.x + c.x; o.y = g.y + c.y;
        int row0 = c_tokoff[v] + c_np[v];
        for (int b = 0; b < 32; ++b)
            *reinterpret_cast<float2*>(out + ((size_t)(b * TOK + row0)) * DM + d2) = o;
        return;
    }

    // ---- block -> (v, h, b, chunk), block-uniform scalar work ----
    int seg = 0;
    while (bid >= c_cum[seg + 1]) ++seg;
    int local = bid - c_cum[seg];
    int v = c_segv[seg];
    int h = local & 1;                           // column half
    int rest = local >> 1;
    int lg = c_lgch[seg];
    int b = rest >> lg;
    int chunk = rest & ((1 << lg) - 1);
    const int pl = c_pl[v];
    const int sf = c_sf[v];
    const int pl2 = pl >> 1;
    const int rpb = c_rpb[v];                    // rows per block
    const int ng  = rpb >> 5;                    // 32-row groups
    const int i0  = chunk * rpb;

    // ---- stage ALL rpb packed patches into LDS as half2 (one pass) ----
    const int ne2 = (rpb * pl) >> 1;             // half2 words (1024 or 2048)
    const float* xb = x + ((size_t)b * NV + v) * LSEQ + (size_t)i0 * (pl * sf);
    if (sf == 1) {
        for (int t = tid; t < (ne2 >> 1); t += NTHR) {   // t = one float4 = 2 words
            float4 q = *reinterpret_cast<const float4*>(xb + 4 * t);
            h2 a; a.x = (_Float16)q.x; a.y = (_Float16)q.y;
            h2 c; c.x = (_Float16)q.z; c.y = (_Float16)q.w;
            uint2 o; o.x = __builtin_bit_cast(unsigned, a);
            o.y = __builtin_bit_cast(unsigned, c);
            *reinterpret_cast<uint2*>(ldsu + 2 * t) = o;
        }
    } else {
        for (int p = tid; p < ne2; p += NTHR) {          // one word per float4
            float4 q = *reinterpret_cast<const float4*>(xb + 4 * p);
            h2 a; a.x = (_Float16)q.x; a.y = (_Float16)q.z;
            ldsu[p] = __builtin_bit_cast(unsigned, a);
        }
    }
    __syncthreads();                             // LDS read-only afterwards

    // ---- per-thread geometry ----
    const int lane = tid & 63;
    const int wv   = tid >> 6;                   // wave -> rows [8wv, 8wv+8) in group
    const int c0   = (h << 8) + (lane << 2);     // 4 consecutive cols (c0 even)
    const unsigned* wtv = reinterpret_cast<const unsigned*>(ws) + c_wtoff[v];

    // bias + channel, hoisted out of the group loop
    const float* bias = (pl == 16) ? b16 : (pl == 32) ? b32 : (pl == 64) ? b64 : b128;
    float4 bc;
    {
        float4 ba = *reinterpret_cast<const float4*>(bias + c0);
        float4 ca = *reinterpret_cast<const float4*>(chan + v * DM + c0);
        bc.x = ba.x + ca.x; bc.y = ba.y + ca.y;
        bc.z = ba.z + ca.z; bc.w = ba.w + ca.w;
    }
    // inline pe divisors (fast trig validated R10/R12-R14; args <= 82 revs)
    const float kc_ = -9.210340371976184f / 512.0f;
    const float div0 = __expf((float)c0 * kc_);
    const float div2 = __expf((float)(c0 + 2) * kc_);

    // ---- row-group loop: R7's exact K-loop per group ----
    for (int g = 0; g < ng; ++g) {
        const unsigned* prow = ldsu + (size_t)(g * 32 + wv * 8) * pl2;

        float acc[8][4];
#pragma unroll
        for (int r = 0; r < 8; ++r)
#pragma unroll
            for (int c = 0; c < 4; ++c) acc[r][c] = 0.f;

        uint4 w0 = *reinterpret_cast<const uint4*>(wtv + c0);
        uint4 w1 = *reinterpret_cast<const uint4*>(wtv + DM + c0);

        for (int k2 = 0; k2 < pl2; k2 += 2) {
            uint4 n0, n1;
            if (k2 + 2 < pl2) {
                const unsigned* wn = wtv + (size_t)(k2 + 2) * DM;
                n0 = *reinterpret_cast<const uint4*>(wn + c0);
                n1 = *reinterpret_cast<const uint4*>(wn + DM + c0);
            }
            uint2 pr[8];
#pragma unroll
            for (int r = 0; r < 8; ++r)
                pr[r] = *reinterpret_cast<const uint2*>(prow + r * pl2 + k2);
#pragma unroll
            for (int r = 0; r < 8; ++r) {
                DOT4(r, bch2(pr[r].x), w0)
                DOT4(r, bch2(pr[r].y), w1)
            }
            w0 = n0; w1 = n1;
        }

        // ---- fp32 epilogue: + bias + channel + inline pe, nt stores ----
        const int row0 = i0 + g * 32 + wv * 8;
        float* ob = out + ((size_t)(b * TOK + c_tokoff[v] + row0)) * DM + c0;
#pragma unroll
        for (int r = 0; r < 8; ++r) {
            float fi = (float)(row0 + r);
            float a0 = fi * div0;
            float a2 = fi * div2;
            float4 o;
            o.x = acc[r][0] + bc.x + __sinf(a0);
            o.y = acc[r][1] + bc.y + __cosf(a0);
            o.z = acc[r][2] + bc.z + __sinf(a2);
            o.w = acc[r][3] + bc.w + __cosf(a2);
            nt_store4(ob + (size_t)r * DM, o);
        }
    }
}

extern "C" void kernel_launch(void* const* d_in, const int* in_sizes, int n_in,
                              void* d_out, int out_size, void* d_ws, size_t ws_size,
                              hipStream_t stream) {
    const float* x    = (const float*)d_in[0];
    const float* w16  = (const float*)d_in[1];
    const float* b16  = (const float*)d_in[2];
    const float* w32  = (const float*)d_in[3];
    const float* b32  = (const float*)d_in[4];
    const float* w64  = (const float*)d_in[5];
    const float* b64  = (const float*)d_in[6];
    const float* w128 = (const float*)d_in[7];
    const float* b128 = (const float*)d_in[8];
    const float* glb  = (const float*)d_in[9];
    const float* chan = (const float*)d_in[10];
    float* out = (float*)d_out;
    float* ws  = (float*)d_ws;   // packed fp16 wt only -> 240 KB

    hipLaunchKernelGGL(setup_kernel, dim3(120), dim3(512), 0, stream,
                       w16, w32, w64, w128, ws);
    hipLaunchKernelGGL(patch_embed_kernel, dim3(1160), dim3(NTHR),
                       2048 * sizeof(unsigned),   // 8 KB dynamic LDS (max ne2)
                       stream,
                       x, b16, b32, b64, b128, glb, chan, ws, out);
}